// Round 1
// baseline (348.783 us; speedup 1.0000x reference)
//
#include <hip/hip_runtime.h>
#include <hip/hip_bf16.h>

// BitLinear forward: out = quant4(x) @ ternary(w)^T + bias
// Factorization: out[m,o] = idot(q[m,:], sign[o,:]) * (max_abs[m]/7) * alpha[o] + bias[o]
// where q in [-8,7] (i8), sign in {-1,0,1} (i8)  -> exact i8 MFMA GEMM + float epilogue.

typedef __attribute__((ext_vector_type(4))) int int32x4;

#define IN_F 1024
#define OUT_F 1024

__device__ inline float waveMax(float v) {
#pragma unroll
    for (int off = 32; off > 0; off >>= 1) v = fmaxf(v, __shfl_xor(v, off, 64));
    return v;
}
__device__ inline float waveSum(float v) {
#pragma unroll
    for (int off = 32; off > 0; off >>= 1) v += __shfl_xor(v, off, 64);
    return v;
}

__device__ inline unsigned int pack4(int a, int b, int c, int d) {
    return (unsigned)(a & 255) | ((unsigned)(b & 255) << 8) |
           ((unsigned)(c & 255) << 16) | ((unsigned)(d & 255) << 24);
}

// ---- W pass 1: alpha[row] = mean(|w[row,:]|) ----------------------------
__global__ __launch_bounds__(256) void wsum_kernel(const float* __restrict__ w,
                                                   float* __restrict__ alpha) {
    __shared__ float red[4];
    const int row = blockIdx.x;
    const int tid = threadIdx.x;
    float4 v = reinterpret_cast<const float4*>(w + (size_t)row * IN_F)[tid];
    float s = fabsf(v.x) + fabsf(v.y) + fabsf(v.z) + fabsf(v.w);
    s = waveSum(s);
    if ((tid & 63) == 0) red[tid >> 6] = s;
    __syncthreads();
    if (tid == 0)
        alpha[row] = (red[0] + red[1] + red[2] + red[3]) * (1.0f / (float)IN_F);
}

// ---- W pass 2: thresh = 0.05*mean(alpha); wq = sign ternary ------------
__global__ __launch_bounds__(256) void wquant_kernel(const float* __restrict__ w,
                                                     const float* __restrict__ alpha,
                                                     signed char* __restrict__ wq) {
    __shared__ float red[4];
    const int tid = threadIdx.x;
    // reduce mean(alpha) over 1024 rows (cheap, redundant per block)
    float4 a = reinterpret_cast<const float4*>(alpha)[tid];
    float s = a.x + a.y + a.z + a.w;
    s = waveSum(s);
    if ((tid & 63) == 0) red[tid >> 6] = s;
    __syncthreads();
    const float thresh =
        0.05f * ((red[0] + red[1] + red[2] + red[3]) * (1.0f / (float)OUT_F));

    const int row = blockIdx.x;
    float4 v = reinterpret_cast<const float4*>(w + (size_t)row * IN_F)[tid];
    int s0 = (fabsf(v.x) < thresh) ? 0 : (v.x > 0.0f ? 1 : -1);
    int s1 = (fabsf(v.y) < thresh) ? 0 : (v.y > 0.0f ? 1 : -1);
    int s2 = (fabsf(v.z) < thresh) ? 0 : (v.z > 0.0f ? 1 : -1);
    int s3 = (fabsf(v.w) < thresh) ? 0 : (v.w > 0.0f ? 1 : -1);
    reinterpret_cast<unsigned int*>(wq)[(size_t)row * (IN_F / 4) + tid] =
        pack4(s0, s1, s2, s3);
}

// ---- X quantize: per-row max_abs, q = clip(rint(x/m*7),-8,7) -----------
__global__ __launch_bounds__(256) void quantx_kernel(const float* __restrict__ x,
                                                     signed char* __restrict__ xq,
                                                     float* __restrict__ sx) {
    __shared__ float red[4];
    const int row = blockIdx.x;
    const int tid = threadIdx.x;
    float4 v = reinterpret_cast<const float4*>(x + (size_t)row * IN_F)[tid];
    float m = fmaxf(fmaxf(fabsf(v.x), fabsf(v.y)), fmaxf(fabsf(v.z), fabsf(v.w)));
    m = waveMax(m);
    if ((tid & 63) == 0) red[tid >> 6] = m;
    __syncthreads();
    m = fmaxf(fmaxf(red[0], red[1]), fmaxf(red[2], red[3]));
    m = fmaxf(m, 1e-6f);
    // match reference op order: (x / m) * 7, round-half-even, clip
    float t0 = fminf(fmaxf(rintf((v.x / m) * 7.0f), -8.0f), 7.0f);
    float t1 = fminf(fmaxf(rintf((v.y / m) * 7.0f), -8.0f), 7.0f);
    float t2 = fminf(fmaxf(rintf((v.z / m) * 7.0f), -8.0f), 7.0f);
    float t3 = fminf(fmaxf(rintf((v.w / m) * 7.0f), -8.0f), 7.0f);
    reinterpret_cast<unsigned int*>(xq)[(size_t)row * (IN_F / 4) + tid] =
        pack4((int)t0, (int)t1, (int)t2, (int)t3);
    if (tid == 0) sx[row] = m / 7.0f;
}

// ---- i8 GEMM: 128x128 block tile, 4 waves (2x2), wave tile 64x64 -------
// Direct global fragment loads (A,B are natural 16B/lane row-major reads).
__global__ __launch_bounds__(256) void gemm_kernel(
    const signed char* __restrict__ xq, const signed char* __restrict__ wq,
    const float* __restrict__ sx, const float* __restrict__ alpha,
    const float* __restrict__ bias, float* __restrict__ out) {
    const int nwg = gridDim.x;
    int bid = blockIdx.x;
    // XCD-aware swizzle (bijective when nwg % 8 == 0)
    if ((nwg & 7) == 0) bid = (bid & 7) * (nwg >> 3) + (bid >> 3);
    const int bn = bid & 7;   // 8 N-tiles (1024/128)
    const int bm = bid >> 3;  // M-tiles

    const int lane = threadIdx.x & 63;
    const int wid = threadIdx.x >> 6;
    const int m_w = bm * 128 + (wid >> 1) * 64;
    const int n_w = bn * 128 + (wid & 1) * 64;
    const int fr = lane & 15;          // fragment row (A) / col-row (B)
    const int koff = (lane >> 4) * 16; // fragment k-offset (bytes)

    const signed char* ap = xq + (size_t)(m_w + fr) * IN_F + koff;
    const signed char* bp = wq + (size_t)(n_w + fr) * IN_F + koff;

    int32x4 acc[4][4];
#pragma unroll
    for (int i = 0; i < 4; ++i)
#pragma unroll
        for (int j = 0; j < 4; ++j) acc[i][j] = (int32x4){0, 0, 0, 0};

    for (int k0 = 0; k0 < IN_F; k0 += 64) {
        int32x4 afr[4], bfr[4];
#pragma unroll
        for (int i = 0; i < 4; ++i)
            afr[i] = *reinterpret_cast<const int32x4*>(ap + (size_t)i * 16 * IN_F + k0);
#pragma unroll
        for (int j = 0; j < 4; ++j)
            bfr[j] = *reinterpret_cast<const int32x4*>(bp + (size_t)j * 16 * IN_F + k0);
#pragma unroll
        for (int i = 0; i < 4; ++i)
#pragma unroll
            for (int j = 0; j < 4; ++j)
                acc[i][j] = __builtin_amdgcn_mfma_i32_16x16x64_i8(afr[i], bfr[j],
                                                                  acc[i][j], 0, 0, 0);
    }

    // epilogue: C/D layout col = lane&15, row = (lane>>4)*4 + reg
    const int crow = (lane >> 4) * 4;
    const int ccol = lane & 15;
#pragma unroll
    for (int j = 0; j < 4; ++j) {
        const int n = n_w + j * 16 + ccol;
        const float al = alpha[n];
        const float bs = bias[n];
#pragma unroll
        for (int i = 0; i < 4; ++i) {
            const int mbase = m_w + i * 16 + crow;
#pragma unroll
            for (int rr = 0; rr < 4; ++rr) {
                const int m = mbase + rr;
                out[(size_t)m * OUT_F + n] =
                    (float)acc[i][j][rr] * (sx[m] * al) + bs;
            }
        }
    }
}

extern "C" void kernel_launch(void* const* d_in, const int* in_sizes, int n_in,
                              void* d_out, int out_size, void* d_ws, size_t ws_size,
                              hipStream_t stream) {
    const float* x = (const float*)d_in[0];
    const float* w = (const float*)d_in[1];
    const float* bias = (const float*)d_in[2];
    float* out = (float*)d_out;
    const int M = in_sizes[0] / IN_F; // 32768

    // workspace layout
    char* ws = (char*)d_ws;
    signed char* xq = (signed char*)ws;                    // M * IN_F  (32 MB)
    signed char* wq = xq + (size_t)M * IN_F;               // 1 MB
    float* sx = (float*)(wq + (size_t)OUT_F * IN_F);       // M floats
    float* alpha = sx + M;                                 // OUT_F floats

    wsum_kernel<<<OUT_F, 256, 0, stream>>>(w, alpha);
    wquant_kernel<<<OUT_F, 256, 0, stream>>>(w, alpha, wq);
    quantx_kernel<<<M, 256, 0, stream>>>(x, xq, sx);
    gemm_kernel<<<(M / 128) * (OUT_F / 128), 256, 0, stream>>>(xq, wq, sx, alpha,
                                                               bias, out);
}

// Round 3
// 346.479 us; speedup vs baseline: 1.0067x; 1.0067x over previous
//
#include <hip/hip_runtime.h>
#include <hip/hip_bf16.h>

// BitLinear forward: out = quant4(x) @ ternary(w)^T + bias
// Factorization: out[m,o] = idot(q[m,:], sign[o,:]) * (max_abs[m]/7) * alpha[o] + bias[o]
// where q in [-8,7] (i8), sign in {-1,0,1} (i8)  -> exact i8 MFMA GEMM + float epilogue.

typedef __attribute__((ext_vector_type(4))) int int32x4;
typedef __attribute__((ext_vector_type(4))) float f32x4;  // native vector: legal for NT builtins

#define IN_F 1024
#define OUT_F 1024

__device__ inline float waveMax(float v) {
#pragma unroll
    for (int off = 32; off > 0; off >>= 1) v = fmaxf(v, __shfl_xor(v, off, 64));
    return v;
}
__device__ inline float waveSum(float v) {
#pragma unroll
    for (int off = 32; off > 0; off >>= 1) v += __shfl_xor(v, off, 64);
    return v;
}

__device__ inline unsigned int pack4(int a, int b, int c, int d) {
    return (unsigned)(a & 255) | ((unsigned)(b & 255) << 8) |
           ((unsigned)(c & 255) << 16) | ((unsigned)(d & 255) << 24);
}

// ---- W pass 1: alpha[row] = mean(|w[row,:]|) ----------------------------
__global__ __launch_bounds__(256) void wsum_kernel(const float* __restrict__ w,
                                                   float* __restrict__ alpha) {
    __shared__ float red[4];
    const int row = blockIdx.x;
    const int tid = threadIdx.x;
    f32x4 v = reinterpret_cast<const f32x4*>(w + (size_t)row * IN_F)[tid];
    float s = fabsf(v.x) + fabsf(v.y) + fabsf(v.z) + fabsf(v.w);
    s = waveSum(s);
    if ((tid & 63) == 0) red[tid >> 6] = s;
    __syncthreads();
    if (tid == 0)
        alpha[row] = (red[0] + red[1] + red[2] + red[3]) * (1.0f / (float)IN_F);
}

// ---- W pass 2: thresh = 0.05*mean(alpha); wq = sign ternary ------------
__global__ __launch_bounds__(256) void wquant_kernel(const float* __restrict__ w,
                                                     const float* __restrict__ alpha,
                                                     signed char* __restrict__ wq) {
    __shared__ float red[4];
    const int tid = threadIdx.x;
    f32x4 a = reinterpret_cast<const f32x4*>(alpha)[tid];
    float s = a.x + a.y + a.z + a.w;
    s = waveSum(s);
    if ((tid & 63) == 0) red[tid >> 6] = s;
    __syncthreads();
    const float thresh =
        0.05f * ((red[0] + red[1] + red[2] + red[3]) * (1.0f / (float)OUT_F));

    const int row = blockIdx.x;
    f32x4 v = reinterpret_cast<const f32x4*>(w + (size_t)row * IN_F)[tid];
    int s0 = (fabsf(v.x) < thresh) ? 0 : (v.x > 0.0f ? 1 : -1);
    int s1 = (fabsf(v.y) < thresh) ? 0 : (v.y > 0.0f ? 1 : -1);
    int s2 = (fabsf(v.z) < thresh) ? 0 : (v.z > 0.0f ? 1 : -1);
    int s3 = (fabsf(v.w) < thresh) ? 0 : (v.w > 0.0f ? 1 : -1);
    reinterpret_cast<unsigned int*>(wq)[(size_t)row * (IN_F / 4) + tid] =
        pack4(s0, s1, s2, s3);
}

// ---- X quantize: WAVE-per-row, no barriers -----------------------------
// Each wave owns one row (1024 floats = 4 f32x4 per lane at stride 64).
__global__ __launch_bounds__(256) void quantx_kernel(const float* __restrict__ x,
                                                     signed char* __restrict__ xq,
                                                     float* __restrict__ sx) {
    const int row = blockIdx.x * 4 + (threadIdx.x >> 6);
    const int lane = threadIdx.x & 63;
    const f32x4* xr = reinterpret_cast<const f32x4*>(x + (size_t)row * IN_F);

    f32x4 v[4];
    float m = 0.0f;
#pragma unroll
    for (int j = 0; j < 4; ++j) {
        v[j] = __builtin_nontemporal_load(&xr[lane + 64 * j]);
        m = fmaxf(m, fmaxf(fmaxf(fabsf(v[j].x), fabsf(v[j].y)),
                           fmaxf(fabsf(v[j].z), fabsf(v[j].w))));
    }
    m = waveMax(m);
    m = fmaxf(m, 1e-6f);

    unsigned int* xqr = reinterpret_cast<unsigned int*>(xq + (size_t)row * IN_F);
#pragma unroll
    for (int j = 0; j < 4; ++j) {
        // match reference op order: (x / m) * 7, round-half-even, clip
        float t0 = fminf(fmaxf(rintf((v[j].x / m) * 7.0f), -8.0f), 7.0f);
        float t1 = fminf(fmaxf(rintf((v[j].y / m) * 7.0f), -8.0f), 7.0f);
        float t2 = fminf(fmaxf(rintf((v[j].z / m) * 7.0f), -8.0f), 7.0f);
        float t3 = fminf(fmaxf(rintf((v[j].w / m) * 7.0f), -8.0f), 7.0f);
        xqr[lane + 64 * j] = pack4((int)t0, (int)t1, (int)t2, (int)t3);
    }
    if (lane == 0) sx[row] = m * (1.0f / 7.0f);
}

// ---- i8 GEMM: 128x128 block tile, 4 waves (2x2), wave tile 64x64 -------
// Direct global fragment loads with explicit 1-deep register double-buffer:
// step t+1's fragments are issued before step t's MFMAs so the compiler can
// keep vmem in flight across the 16 MFMAs (all indices compile-time).
__global__ __launch_bounds__(256) void gemm_kernel(
    const signed char* __restrict__ xq, const signed char* __restrict__ wq,
    const float* __restrict__ sx, const float* __restrict__ alpha,
    const float* __restrict__ bias, float* __restrict__ out) {
    const int nwg = gridDim.x;
    int bid = blockIdx.x;
    // XCD-aware swizzle (bijective when nwg % 8 == 0)
    if ((nwg & 7) == 0) bid = (bid & 7) * (nwg >> 3) + (bid >> 3);
    const int bn = bid & 7;   // 8 N-tiles (1024/128)
    const int bm = bid >> 3;  // M-tiles

    const int lane = threadIdx.x & 63;
    const int wid = threadIdx.x >> 6;
    const int m_w = bm * 128 + (wid >> 1) * 64;
    const int n_w = bn * 128 + (wid & 1) * 64;
    const int fr = lane & 15;          // fragment row
    const int koff = (lane >> 4) * 16; // fragment k-offset (bytes)

    const signed char* ap = xq + (size_t)(m_w + fr) * IN_F + koff;
    const signed char* bp = wq + (size_t)(n_w + fr) * IN_F + koff;

    int32x4 acc[4][4];
#pragma unroll
    for (int i = 0; i < 4; ++i)
#pragma unroll
        for (int j = 0; j < 4; ++j) acc[i][j] = (int32x4){0, 0, 0, 0};

    int32x4 afr[2][4], bfr[2][4];
#pragma unroll
    for (int i = 0; i < 4; ++i)
        afr[0][i] = *reinterpret_cast<const int32x4*>(ap + (size_t)i * 16 * IN_F);
#pragma unroll
    for (int j = 0; j < 4; ++j)
        bfr[0][j] = *reinterpret_cast<const int32x4*>(bp + (size_t)j * 16 * IN_F);

#pragma unroll
    for (int t = 0; t < 16; ++t) {
        const int cur = t & 1, nxt = cur ^ 1;
        if (t < 15) {
            const int k1 = (t + 1) * 64;
#pragma unroll
            for (int i = 0; i < 4; ++i)
                afr[nxt][i] = *reinterpret_cast<const int32x4*>(
                    ap + (size_t)i * 16 * IN_F + k1);
#pragma unroll
            for (int j = 0; j < 4; ++j)
                bfr[nxt][j] = *reinterpret_cast<const int32x4*>(
                    bp + (size_t)j * 16 * IN_F + k1);
        }
#pragma unroll
        for (int i = 0; i < 4; ++i)
#pragma unroll
            for (int j = 0; j < 4; ++j)
                acc[i][j] = __builtin_amdgcn_mfma_i32_16x16x64_i8(
                    afr[cur][i], bfr[cur][j], acc[i][j], 0, 0, 0);
    }

    // epilogue: C/D layout col = lane&15, row = (lane>>4)*4 + reg
    const int crow = (lane >> 4) * 4;
    const int ccol = lane & 15;
#pragma unroll
    for (int j = 0; j < 4; ++j) {
        const int n = n_w + j * 16 + ccol;
        const float al = alpha[n];
        const float bs = bias[n];
#pragma unroll
        for (int i = 0; i < 4; ++i) {
            const int mbase = m_w + i * 16 + crow;
#pragma unroll
            for (int rr = 0; rr < 4; ++rr) {
                const int m = mbase + rr;
                __builtin_nontemporal_store(
                    (float)acc[i][j][rr] * (sx[m] * al) + bs,
                    &out[(size_t)m * OUT_F + n]);
            }
        }
    }
}

extern "C" void kernel_launch(void* const* d_in, const int* in_sizes, int n_in,
                              void* d_out, int out_size, void* d_ws, size_t ws_size,
                              hipStream_t stream) {
    const float* x = (const float*)d_in[0];
    const float* w = (const float*)d_in[1];
    const float* bias = (const float*)d_in[2];
    float* out = (float*)d_out;
    const int M = in_sizes[0] / IN_F; // 32768

    // workspace layout
    char* ws = (char*)d_ws;
    signed char* xq = (signed char*)ws;                    // M * IN_F  (32 MB)
    signed char* wq = xq + (size_t)M * IN_F;               // 1 MB
    float* sx = (float*)(wq + (size_t)OUT_F * IN_F);       // M floats
    float* alpha = sx + M;                                 // OUT_F floats

    wsum_kernel<<<OUT_F, 256, 0, stream>>>(w, alpha);
    wquant_kernel<<<OUT_F, 256, 0, stream>>>(w, alpha, wq);
    quantx_kernel<<<M / 4, 256, 0, stream>>>(x, xq, sx);
    gemm_kernel<<<(M / 128) * (OUT_F / 128), 256, 0, stream>>>(xq, wq, sx, alpha,
                                                               bias, out);
}

// Round 4
// 308.252 us; speedup vs baseline: 1.1315x; 1.1240x over previous
//
#include <hip/hip_runtime.h>
#include <hip/hip_bf16.h>

// BitLinear forward: out = quant4(x) @ ternary(w)^T + bias
// Factorization: out[m,o] = idot(q[m,:], sign[o,:]) * (max_abs[m]/7) * alpha[o] + bias[o]
// where q in [-8,7] (i8), sign in {-1,0,1} (i8)  -> exact i8 MFMA GEMM + float epilogue.

typedef __attribute__((ext_vector_type(4))) int int32x4;
typedef __attribute__((ext_vector_type(4))) float f32x4;

#define IN_F 1024
#define OUT_F 1024

__device__ inline float waveMax(float v) {
#pragma unroll
    for (int off = 32; off > 0; off >>= 1) v = fmaxf(v, __shfl_xor(v, off, 64));
    return v;
}
__device__ inline float waveSum(float v) {
#pragma unroll
    for (int off = 32; off > 0; off >>= 1) v += __shfl_xor(v, off, 64);
    return v;
}

__device__ inline unsigned int pack4(int a, int b, int c, int d) {
    return (unsigned)(a & 255) | ((unsigned)(b & 255) << 8) |
           ((unsigned)(c & 255) << 16) | ((unsigned)(d & 255) << 24);
}

// async global->LDS, 16B per lane. LDS dst = wave-uniform base + lane*16.
__device__ inline void gll16(const void* g, void* l) {
    __builtin_amdgcn_global_load_lds(
        (const __attribute__((address_space(1))) void*)g,
        (__attribute__((address_space(3))) void*)l, 16, 0, 0);
}

// ---- W pass 1: alpha[row] = mean(|w[row,:]|) ----------------------------
__global__ __launch_bounds__(256) void wsum_kernel(const float* __restrict__ w,
                                                   float* __restrict__ alpha) {
    __shared__ float red[4];
    const int row = blockIdx.x;
    const int tid = threadIdx.x;
    f32x4 v = reinterpret_cast<const f32x4*>(w + (size_t)row * IN_F)[tid];
    float s = fabsf(v.x) + fabsf(v.y) + fabsf(v.z) + fabsf(v.w);
    s = waveSum(s);
    if ((tid & 63) == 0) red[tid >> 6] = s;
    __syncthreads();
    if (tid == 0)
        alpha[row] = (red[0] + red[1] + red[2] + red[3]) * (1.0f / (float)IN_F);
}

// ---- W pass 2: thresh = 0.05*mean(alpha); wq = sign ternary ------------
__global__ __launch_bounds__(256) void wquant_kernel(const float* __restrict__ w,
                                                     const float* __restrict__ alpha,
                                                     signed char* __restrict__ wq) {
    __shared__ float red[4];
    const int tid = threadIdx.x;
    f32x4 a = reinterpret_cast<const f32x4*>(alpha)[tid];
    float s = a.x + a.y + a.z + a.w;
    s = waveSum(s);
    if ((tid & 63) == 0) red[tid >> 6] = s;
    __syncthreads();
    const float thresh =
        0.05f * ((red[0] + red[1] + red[2] + red[3]) * (1.0f / (float)OUT_F));

    const int row = blockIdx.x;
    f32x4 v = reinterpret_cast<const f32x4*>(w + (size_t)row * IN_F)[tid];
    int s0 = (fabsf(v.x) < thresh) ? 0 : (v.x > 0.0f ? 1 : -1);
    int s1 = (fabsf(v.y) < thresh) ? 0 : (v.y > 0.0f ? 1 : -1);
    int s2 = (fabsf(v.z) < thresh) ? 0 : (v.z > 0.0f ? 1 : -1);
    int s3 = (fabsf(v.w) < thresh) ? 0 : (v.w > 0.0f ? 1 : -1);
    reinterpret_cast<unsigned int*>(wq)[(size_t)row * (IN_F / 4) + tid] =
        pack4(s0, s1, s2, s3);
}

// ---- X quantize: WAVE-per-row, no barriers (unchanged from r3) ---------
__global__ __launch_bounds__(256) void quantx_kernel(const float* __restrict__ x,
                                                     signed char* __restrict__ xq,
                                                     float* __restrict__ sx) {
    const int row = blockIdx.x * 4 + (threadIdx.x >> 6);
    const int lane = threadIdx.x & 63;
    const f32x4* xr = reinterpret_cast<const f32x4*>(x + (size_t)row * IN_F);

    f32x4 v[4];
    float m = 0.0f;
#pragma unroll
    for (int j = 0; j < 4; ++j) {
        v[j] = __builtin_nontemporal_load(&xr[lane + 64 * j]);
        m = fmaxf(m, fmaxf(fmaxf(fabsf(v[j].x), fabsf(v[j].y)),
                           fmaxf(fabsf(v[j].z), fabsf(v[j].w))));
    }
    m = waveMax(m);
    m = fmaxf(m, 1e-6f);

    unsigned int* xqr = reinterpret_cast<unsigned int*>(xq + (size_t)row * IN_F);
#pragma unroll
    for (int j = 0; j < 4; ++j) {
        float t0 = fminf(fmaxf(rintf((v[j].x / m) * 7.0f), -8.0f), 7.0f);
        float t1 = fminf(fmaxf(rintf((v[j].y / m) * 7.0f), -8.0f), 7.0f);
        float t2 = fminf(fmaxf(rintf((v[j].z / m) * 7.0f), -8.0f), 7.0f);
        float t3 = fminf(fmaxf(rintf((v[j].w / m) * 7.0f), -8.0f), 7.0f);
        xqr[lane + 64 * j] = pack4((int)t0, (int)t1, (int)t2, (int)t3);
    }
    if (lane == 0) sx[row] = m * (1.0f / 7.0f);
}

// ---- i8 GEMM: 128x128 tile, BK=64, LDS double-buffered (m97 structure) --
// LDS layout is FRAGMENT-LINEAR: chunk f (1KB) holds the exact 64-lane MFMA
// fragment for rows (f>>2)*64 + (f&3)*16 + (lane&15), kbytes (lane>>4)*16.
// => every ds_read_b128 is base + lane*16 (zero bank conflicts), and
// global_load_lds writes it with per-lane global addresses (LDS stays linear).
__global__ __launch_bounds__(256) void gemm_kernel(
    const signed char* __restrict__ xq, const signed char* __restrict__ wq,
    const float* __restrict__ sx, const float* __restrict__ alpha,
    const float* __restrict__ bias, float* __restrict__ out) {
    __shared__ signed char lds[2][2][8192];  // [buf][A/B][bytes] = 32 KiB

    const int nwg = gridDim.x;
    int bid = blockIdx.x;
    if ((nwg & 7) == 0) bid = (bid & 7) * (nwg >> 3) + (bid >> 3);  // XCD swizzle
    const int bn = bid & 7;   // 8 N-tiles
    const int bm = bid >> 3;  // M-tiles
    const int m_b = bm * 128;
    const int n_b = bn * 128;

    const int lane = threadIdx.x & 63;
    const int wid = threadIdx.x >> 6;

    // staging: wave wid, inst c covers chunk f = c*4+wid
    //   lane reads global row  c*64 + wid*16 + (lane&15), kbyte (lane>>4)*16
    const int srow = wid * 16 + (lane & 15);
    const int skb = (lane >> 4) * 16;
    const signed char* aSrc0 = xq + (size_t)(m_b + srow) * IN_F + skb;
    const signed char* aSrc1 = xq + (size_t)(m_b + 64 + srow) * IN_F + skb;
    const signed char* bSrc0 = wq + (size_t)(n_b + srow) * IN_F + skb;
    const signed char* bSrc1 = wq + (size_t)(n_b + 64 + srow) * IN_F + skb;
    const int ldsA0 = wid * 1024;         // chunk f = wid
    const int ldsA1 = 4096 + wid * 1024;  // chunk f = 4+wid

    // fragment-read bases (wave tile: 64x64; wmh/wnh select tile half)
    const int wmh = wid >> 1, wnh = wid & 1;
    const int aOff = wmh * 4096 + lane * 16;  // + i*1024
    const int bOff = wnh * 4096 + lane * 16;  // + j*1024

    int32x4 acc[4][4];
#pragma unroll
    for (int i = 0; i < 4; ++i)
#pragma unroll
        for (int j = 0; j < 4; ++j) acc[i][j] = (int32x4){0, 0, 0, 0};

    // prologue: stage K-step 0 into buf 0
    gll16(aSrc0, &lds[0][0][ldsA0]);
    gll16(aSrc1, &lds[0][0][ldsA1]);
    gll16(bSrc0, &lds[0][1][ldsA0]);
    gll16(bSrc1, &lds[0][1][ldsA1]);

#pragma unroll
    for (int t = 0; t < 16; ++t) {
        const int cur = t & 1;
        __syncthreads();  // buf[cur] staged by all waves; prev reads done
        if (t < 15) {
            const int k1 = (t + 1) * 64;
            gll16(aSrc0 + k1, &lds[cur ^ 1][0][ldsA0]);
            gll16(aSrc1 + k1, &lds[cur ^ 1][0][ldsA1]);
            gll16(bSrc0 + k1, &lds[cur ^ 1][1][ldsA0]);
            gll16(bSrc1 + k1, &lds[cur ^ 1][1][ldsA1]);
        }
        int32x4 afr[4], bfr[4];
#pragma unroll
        for (int i = 0; i < 4; ++i)
            afr[i] = *reinterpret_cast<const int32x4*>(&lds[cur][0][aOff + i * 1024]);
#pragma unroll
        for (int j = 0; j < 4; ++j)
            bfr[j] = *reinterpret_cast<const int32x4*>(&lds[cur][1][bOff + j * 1024]);
#pragma unroll
        for (int i = 0; i < 4; ++i)
#pragma unroll
            for (int j = 0; j < 4; ++j)
                acc[i][j] = __builtin_amdgcn_mfma_i32_16x16x64_i8(afr[i], bfr[j],
                                                                  acc[i][j], 0, 0, 0);
    }

    // epilogue: C/D layout col = lane&15, row = (lane>>4)*4 + reg
    const int m_w = m_b + wmh * 64;
    const int n_w = n_b + wnh * 64;
    const int crow = (lane >> 4) * 4;
    const int ccol = lane & 15;
#pragma unroll
    for (int j = 0; j < 4; ++j) {
        const int n = n_w + j * 16 + ccol;
        const float al = alpha[n];
        const float bs = bias[n];
#pragma unroll
        for (int i = 0; i < 4; ++i) {
            const int mbase = m_w + i * 16 + crow;
#pragma unroll
            for (int rr = 0; rr < 4; ++rr) {
                const int m = mbase + rr;
                out[(size_t)m * OUT_F + n] = (float)acc[i][j][rr] * (sx[m] * al) + bs;
            }
        }
    }
}

extern "C" void kernel_launch(void* const* d_in, const int* in_sizes, int n_in,
                              void* d_out, int out_size, void* d_ws, size_t ws_size,
                              hipStream_t stream) {
    const float* x = (const float*)d_in[0];
    const float* w = (const float*)d_in[1];
    const float* bias = (const float*)d_in[2];
    float* out = (float*)d_out;
    const int M = in_sizes[0] / IN_F;  // 32768

    char* ws = (char*)d_ws;
    signed char* xq = (signed char*)ws;               // 32 MB
    signed char* wq = xq + (size_t)M * IN_F;          // 1 MB
    float* sx = (float*)(wq + (size_t)OUT_F * IN_F);  // M floats
    float* alpha = sx + M;                            // OUT_F floats

    wsum_kernel<<<OUT_F, 256, 0, stream>>>(w, alpha);
    wquant_kernel<<<OUT_F, 256, 0, stream>>>(w, alpha, wq);
    quantx_kernel<<<M / 4, 256, 0, stream>>>(x, xq, sx);
    gemm_kernel<<<(M / 128) * (OUT_F / 128), 256, 0, stream>>>(xq, wq, sx, alpha,
                                                               bias, out);
}